// Round 7
// baseline (70.865 us; speedup 1.0000x reference)
//
#include <hip/hip_runtime.h>

#define NATOMS 16

// One block = one (molecule, center-atom): grid = nmol*16, 64 threads = 1 wave.
// Single-wave workgroup: __syncthreads() lowers to s_waitcnt only (no s_barrier).
__global__ __launch_bounds__(64, 8) void aev_kernel(const int* __restrict__ species,
                                                    const float* __restrict__ coords,
                                                    float* __restrict__ out,
                                                    int nmol) {
    const int l = threadIdx.x;           // lane 0..63
    const int bid = blockIdx.x;
    const int b = bid >> 4;              // molecule
    const int i = bid & 15;              // center atom

    __shared__ float scm[48];            // coords of this molecule, packed
    __shared__ int   ssp[16];
    __shared__ float dX[16], dY[16], dZ[16], sD[16], sRinv[16], sFca[16], sFcr4[16];
    __shared__ float rad[16][17];        // padded
    __shared__ int   hist[10], sBase[10], sCur[10];
    __shared__ float4 ebuf[105];         // (ca, sa, t0, r1); max C(15,2)=105 triples

    // ---- phase 0: loads + per-lane angular constants ----
    if (l < 48) scm[l] = coords[b * 48 + l];
    if (l < 16) {
        int sp = species[b * 16 + l];
        ssp[l] = sp;
        if (i == 0) out[b * 16 + l] = (float)sp;   // species output (as float)
    }
    if (l < 10) hist[l] = 0;

    const int f = l & 31;                // angular feature id for phase B
    const int z = f & 7, a = f >> 3;
    const float ang = (2.0f * (float)z + 1.0f) * 0.19634954084936207f;  // (2z+1)*pi/16
    const float czh = 0.5f * __cosf(ang);
    const float szh = 0.5f * __sinf(ang);
    const float ga  = __expf(-3.38f * (float)(a * a - a));  // exp(-6.76 * a(a-1)/2)
    __syncthreads();

    const int spi = ssp[i];
    const float xi = scm[3 * i], yi = scm[3 * i + 1], zi = scm[3 * i + 2];

    // ---- phase 1: per-j pair quantities (lanes 0..15) ----
    if (l < 16) {
        const int jj = l;
        float dx = xi - scm[3 * jj], dy = yi - scm[3 * jj + 1], dz = zi - scm[3 * jj + 2];
        bool pv = (jj != i) && (spi >= 0) && (ssp[jj] >= 0);
        float d2 = dx * dx + dy * dy + dz * dz;
        float d = sqrtf(pv ? d2 : 1.0f);
        float rinv = 1.0f / d;
        float fca = (pv && d <= 3.5f) ? (0.5f * __cosf(d * 0.8975979010256552f) + 0.5f) : 0.0f;
        float fcr = (pv && d <= 5.2f) ? (0.5f * __cosf(d * 0.6041515809446141f) + 0.5f) : 0.0f;
        dX[jj] = dx; dY[jj] = dy; dZ[jj] = dz;
        sD[jj] = d; sRinv[jj] = rinv; sFca[jj] = fca; sFcr4[jj] = 0.25f * fcr;
    }
    __syncthreads();

    // ---- phase 1b: radial terms, 4 exps per lane (64 lanes = 16 j x 4 r-groups) ----
    {
        const int jj = l & 15, rg = l >> 4;
        float d = sD[jj], f4 = sFcr4[jj];
        #pragma unroll
        for (int rr = 0; rr < 4; ++rr) {
            int r = rg * 4 + rr;
            float e = d - (0.9f + 0.26875f * (float)r);
            rad[jj][r] = f4 * __expf(-16.0f * e * e);
        }
    }

    // ---- phase 2a: decode unordered (j<k) slots [0,120), filter, histogram ----
    int j1 = -1, k1 = -1, p1 = -1, j2 = -1, k2 = -1, p2 = -1;
    {
        int s = l;
        float sq = sqrtf((float)(961 - 8 * s));
        int j = (int)floorf((31.0f - sq) * 0.5f);
        j = j < 0 ? 0 : (j > 14 ? 14 : j);
        int off = (j * (31 - j)) >> 1;
        if (s < off) { --j; off = (j * (31 - j)) >> 1; }
        else { int off2 = ((j + 1) * (30 - j)) >> 1; if (s >= off2) { ++j; off = off2; } }
        int k = j + 1 + (s - off);
        if (sFca[j] > 0.f && sFca[k] > 0.f) {
            int s1 = ssp[j], s2 = ssp[k];
            int lo = s1 < s2 ? s1 : s2, hi = s1 < s2 ? s2 : s1;
            p1 = lo * 4 + hi - ((lo * (lo + 1)) >> 1);
            j1 = j; k1 = k;
            atomicAdd(&hist[p1], 1);
        }
    }
    if (l < 56) {
        int s = l + 64;
        float sq = sqrtf((float)(961 - 8 * s));
        int j = (int)floorf((31.0f - sq) * 0.5f);
        j = j < 0 ? 0 : (j > 14 ? 14 : j);
        int off = (j * (31 - j)) >> 1;
        if (s < off) { --j; off = (j * (31 - j)) >> 1; }
        else { int off2 = ((j + 1) * (30 - j)) >> 1; if (s >= off2) { ++j; off = off2; } }
        int k = j + 1 + (s - off);
        if (sFca[j] > 0.f && sFca[k] > 0.f) {
            int s1 = ssp[j], s2 = ssp[k];
            int lo = s1 < s2 ? s1 : s2, hi = s1 < s2 ? s2 : s1;
            p2 = lo * 4 + hi - ((lo * (lo + 1)) >> 1);
            j2 = j; k2 = k;
            atomicAdd(&hist[p2], 1);
        }
    }
    __syncthreads();

    // ---- phase 2b: exclusive prefix over 10 buckets ----
    if (l < 10) {
        int sum = 0;
        for (int qq = 0; qq < l; ++qq) sum += hist[qq];
        sBase[l] = sum;
        sCur[l] = sum;
    }
    __syncthreads();

    // ---- phase 2c: fill buckets with (ca, sa, t0, r1) ----
    #pragma unroll
    for (int slot = 0; slot < 2; ++slot) {
        int jj = slot == 0 ? j1 : j2;
        int kk = slot == 0 ? k1 : k2;
        int pp = slot == 0 ? p1 : p2;
        if (jj >= 0) {
            float fj = sFca[jj], fk = sFca[kk];
            float dot = dX[jj] * dX[kk] + dY[jj] * dY[kk] + dZ[jj] * dZ[kk];
            float ca = 0.95f * dot * sRinv[jj] * sRinv[kk];
            ca = fminf(0.95f, fmaxf(-0.95f, ca));
            float sa = sqrtf(1.0f - ca * ca);        // sin(arccos(ca))
            float davg = 0.5f * (sD[jj] + sD[kk]);
            float e0 = davg - 0.9f;
            float t0 = 2.0f * fj * fk * __expf(-8.0f * e0 * e0);
            float r1 = __expf(10.4f * davg - 12.74f);
            int idx = atomicAdd(&sCur[pp], 1);
            ebuf[idx] = make_float4(ca, sa, t0, r1);
        }
    }
    __syncthreads();

    // ---- phase B: angular gather; lane = (p-half, f) ----
    float* base_o = out + (size_t)nmol * 16 + (size_t)(b * 16 + i) * 384;
    {
        const int half = l >> 5;
        const bool a1 = (a & 1), a2 = (a & 2) != 0;
        #pragma unroll
        for (int pp = 0; pp < 5; ++pp) {
            int p = pp * 2 + half;
            int st = sBase[p];
            int n = hist[p];
            float acc = 0.0f;
            for (int e = 0; e < n; ++e) {
                float4 v = ebuf[st + e];
                float c1 = fmaf(czh, v.x, fmaf(szh, v.y, 0.5f));  // (1+cos(th-shfz))/2
                float c2 = c1 * c1;
                float c4 = c2 * c2;
                float c8 = c4 * c4;
                float c16 = c8 * c8;
                float c32 = c16 * c16;
                float tt = v.z;
                float rsq = v.w * v.w;
                tt = a1 ? tt * v.w : tt;
                tt = a2 ? tt * rsq : tt;                           // tt = t0 * r1^a
                acc = fmaf(tt, c32, acc);
            }
            base_o[64 + p * 32 + f] = acc * ga;
        }
    }

    // ---- phase R: radial gather; lane = (species, r) ----
    {
        const int s_ = l >> 4, r_ = l & 15;
        float rv = 0.0f;
        #pragma unroll
        for (int jj = 0; jj < 16; ++jj)
            rv += (ssp[jj] == s_) ? rad[jj][r_] : 0.0f;
        base_o[l] = rv;
    }
}

extern "C" void kernel_launch(void* const* d_in, const int* in_sizes, int n_in,
                              void* d_out, int out_size, void* d_ws, size_t ws_size,
                              hipStream_t stream) {
    const int*   species = (const int*)d_in[0];
    const float* coords  = (const float*)d_in[1];
    float*       out     = (float*)d_out;
    int nmol = in_sizes[0] / NATOMS;   // 512
    aev_kernel<<<nmol * 16, 64, 0, stream>>>(species, coords, out, nmol);
}

// Round 9
// 70.744 us; speedup vs baseline: 1.0017x; 1.0017x over previous
//
#include <hip/hip_runtime.h>

#define NATOMS 16

// LUT: unordered pair slot s in [0,120) -> (j<<4)|k, j<k in [0,16)
struct TriTab {
    unsigned char v[120];
    constexpr TriTab() : v() {
        int s = 0;
        for (int j = 0; j < 15; ++j)
            for (int k = j + 1; k < 16; ++k)
                v[s++] = (unsigned char)((j << 4) | k);
    }
};
__constant__ TriTab TRI = TriTab();

// One block = one (molecule, center-atom): grid = nmol*16, 64 threads = 1 wave.
__global__ __launch_bounds__(64, 8) void aev_kernel(const int* __restrict__ species,
                                                    const float* __restrict__ coords,
                                                    float* __restrict__ out,
                                                    int nmol) {
    const int l = threadIdx.x;           // lane 0..63
    const int bid = blockIdx.x;
    const int b = bid >> 4;              // molecule
    const int i = bid & 15;              // center atom

    __shared__ float scm[48];            // packed coords of this molecule
    __shared__ int   ssp[16];
    __shared__ float rad[16][17];        // padded
    __shared__ int   hist[10], sBase[10], sCur[10];
    __shared__ float4 ebuf[105];         // (ca, sa, t0, r1); max C(15,2)=105 triples

    // ---- issue LUT + global loads first (all independent) ----
    const unsigned jk0 = TRI.v[l];                       // slot s = l
    const unsigned jk1 = (l < 56) ? TRI.v[64 + l] : 0u;  // slot s = 64+l

    if (l < 48) scm[l] = coords[b * 48 + l];
    if (l < 16) {
        int sp = species[b * 16 + l];
        ssp[l] = sp;
        if (i == 0) out[b * 16 + l] = (float)sp;         // species output (as float)
    }
    if (l < 10) hist[l] = 0;

    // per-lane angular constants (registers)
    const int f = l & 31;
    const int z = f & 7, a = f >> 3;
    const float ang = (2.0f * (float)z + 1.0f) * 0.19634954084936207f;  // (2z+1)*pi/16
    const float czh = 0.5f * __cosf(ang);
    const float szh = 0.5f * __sinf(ang);
    const float ga  = __expf(-3.38f * (float)(a * a - a));
    __syncthreads();

    const int spi = ssp[i];
    const float xi = scm[3 * i], yi = scm[3 * i + 1], zi = scm[3 * i + 2];

    // register-resident pair quantities for atom jj vs center i
    auto pairq = [&](int jj, float& dx, float& dy, float& dz, float& d, float& fca) {
        dx = xi - scm[3 * jj]; dy = yi - scm[3 * jj + 1]; dz = zi - scm[3 * jj + 2];
        bool pv = (jj != i) && (spi >= 0) && (ssp[jj] >= 0);
        float d2 = dx * dx + dy * dy + dz * dz;
        d = sqrtf(pv ? d2 : 1.0f);
        fca = (pv && d <= 3.5f) ? fmaf(0.5f, __cosf(d * 0.8975979010256552f), 0.5f) : 0.0f;
    };

    // ---- slot 0: triple s = l ----
    float ca0 = 0.f, sa0 = 0.f, t00 = 0.f, r10 = 0.f; int p0 = -1;
    {
        const int j = jk0 >> 4, k = jk0 & 15;
        float dxj, dyj, dzj, dj, fcaj, dxk, dyk, dzk, dk, fcak;
        pairq(j, dxj, dyj, dzj, dj, fcaj);
        pairq(k, dxk, dyk, dzk, dk, fcak);
        if (fcaj > 0.0f && fcak > 0.0f) {
            float dot = dxj * dxk + dyj * dyk + dzj * dzk;
            float ca = __fdividef(0.95f * dot, dj * dk);
            ca = fminf(0.95f, fmaxf(-0.95f, ca));
            sa0 = sqrtf(1.0f - ca * ca);
            ca0 = ca;
            float davg = 0.5f * (dj + dk);
            float e0 = davg - 0.9f;
            t00 = 2.0f * fcaj * fcak * __expf(-8.0f * e0 * e0);
            r10 = __expf(10.4f * davg - 12.74f);
            int sj = ssp[j], sk = ssp[k];
            int lo = sj < sk ? sj : sk, hi = sj < sk ? sk : sj;
            p0 = lo * 4 + hi - ((lo * (lo + 1)) >> 1);
            atomicAdd(&hist[p0], 1);
        }
    }

    // ---- slot 1: triple s = 64 + l (l < 56) ----
    float ca1 = 0.f, sa1 = 0.f, t01 = 0.f, r11 = 0.f; int p1 = -1;
    if (l < 56) {
        const int j = jk1 >> 4, k = jk1 & 15;
        float dxj, dyj, dzj, dj, fcaj, dxk, dyk, dzk, dk, fcak;
        pairq(j, dxj, dyj, dzj, dj, fcaj);
        pairq(k, dxk, dyk, dzk, dk, fcak);
        if (fcaj > 0.0f && fcak > 0.0f) {
            float dot = dxj * dxk + dyj * dyk + dzj * dzk;
            float ca = __fdividef(0.95f * dot, dj * dk);
            ca = fminf(0.95f, fmaxf(-0.95f, ca));
            sa1 = sqrtf(1.0f - ca * ca);
            ca1 = ca;
            float davg = 0.5f * (dj + dk);
            float e0 = davg - 0.9f;
            t01 = 2.0f * fcaj * fcak * __expf(-8.0f * e0 * e0);
            r11 = __expf(10.4f * davg - 12.74f);
            int sj = ssp[j], sk = ssp[k];
            int lo = sj < sk ? sj : sk, hi = sj < sk ? sk : sj;
            p1 = lo * 4 + hi - ((lo * (lo + 1)) >> 1);
            atomicAdd(&hist[p1], 1);
        }
    }

    // ---- radial terms (independent work covering hist-atomic latency) ----
    {
        const int jj = l & 15, rg = l >> 4;
        float dx = xi - scm[3 * jj], dy = yi - scm[3 * jj + 1], dz = zi - scm[3 * jj + 2];
        bool pv = (jj != i) && (spi >= 0) && (ssp[jj] >= 0);
        float d = sqrtf(dx * dx + dy * dy + dz * dz);
        float fcr4 = (pv && d <= 5.2f)
                   ? 0.25f * fmaf(0.5f, __cosf(d * 0.6041515809446141f), 0.5f) : 0.0f;
        #pragma unroll
        for (int rr = 0; rr < 4; ++rr) {
            int r = rg * 4 + rr;
            float e = d - (0.9f + 0.26875f * (float)r);
            rad[jj][r] = fcr4 * __expf(-16.0f * e * e);
        }
    }
    __syncthreads();

    // ---- exclusive prefix over 10 buckets ----
    if (l < 10) {
        int sum = 0;
        for (int qq = 0; qq < l; ++qq) sum += hist[qq];
        sBase[l] = sum;
        sCur[l] = sum;
    }
    __syncthreads();

    // ---- bucket fill ----
    if (p0 >= 0) { int idx = atomicAdd(&sCur[p0], 1); ebuf[idx] = make_float4(ca0, sa0, t00, r10); }
    if (p1 >= 0) { int idx = atomicAdd(&sCur[p1], 1); ebuf[idx] = make_float4(ca1, sa1, t01, r11); }
    __syncthreads();

    // ---- phase B: angular gather; lane = (p-half, f) ----
    float* base_o = out + (size_t)nmol * 16 + (size_t)(b * 16 + i) * 384;
    {
        const int half = l >> 5;
        const bool a1 = (a & 1), a2 = (a & 2) != 0;
        #pragma unroll
        for (int pp = 0; pp < 5; ++pp) {
            int p = pp * 2 + half;
            int st = sBase[p];
            int n = hist[p];
            float acc = 0.0f;
            for (int e = 0; e < n; ++e) {
                float4 v = ebuf[st + e];
                float c1 = fmaf(czh, v.x, fmaf(szh, v.y, 0.5f));  // (1+cos(th-shfz))/2
                float c2 = c1 * c1;
                float c4 = c2 * c2;
                float c8 = c4 * c4;
                float c16 = c8 * c8;
                float c32 = c16 * c16;
                float tt = v.z;
                float rsq = v.w * v.w;
                tt = a1 ? tt * v.w : tt;
                tt = a2 ? tt * rsq : tt;                           // tt = t0 * r1^a
                acc = fmaf(tt, c32, acc);
            }
            base_o[64 + p * 32 + f] = acc * ga;
        }
    }

    // ---- phase R: radial gather; lane = (species, r) ----
    {
        const int s_ = l >> 4, r_ = l & 15;
        float rv = 0.0f;
        #pragma unroll
        for (int jj = 0; jj < 16; ++jj)
            rv += (ssp[jj] == s_) ? rad[jj][r_] : 0.0f;
        base_o[l] = rv;
    }
}

extern "C" void kernel_launch(void* const* d_in, const int* in_sizes, int n_in,
                              void* d_out, int out_size, void* d_ws, size_t ws_size,
                              hipStream_t stream) {
    const int*   species = (const int*)d_in[0];
    const float* coords  = (const float*)d_in[1];
    float*       out     = (float*)d_out;
    int nmol = in_sizes[0] / NATOMS;   // 512
    aev_kernel<<<nmol * 16, 64, 0, stream>>>(species, coords, out, nmol);
}